// Round 5
// baseline (115.281 us; speedup 1.0000x reference)
//
#include <hip/hip_runtime.h>

// SNN policy rollout, fully fused. B=32768 rows, H=64 hidden, O=4 outputs, T=16 steps.
//
// Mapping (r3): 256-thread block = 4 waves = 16 rows. Per wave: 4 rows x 16
// lanes/row, each lane owns 4 h-channels (h = li*4 .. li*4+3, contiguous float4).
// Was 8 rows x 8 lanes x 8 ch: halving per-lane state (~120 -> ~80 VGPR) removes
// the spill cliff at the __launch_bounds__(256,4) 128-VGPR cap and doubles wave
// count (8192 waves -> 8/SIMD) for latency hiding. Threshold-path numerics are
// bit-identical to the r2 kernel (per-channel recurrence + ch[k] fma chain are
// elementwise); only the ia butterfly order changes (continuous path, ~1e-7).
//
// All recurrent state in registers; ia-reduction via 4-step __shfl_xor butterfly
// within each 16-lane row group; softmax over O=4 replicated across the group
// (replication is free: wave64 lanes run in lockstep).
// val output is exactly 16.0 (softmax of a [B,1] tensor is bitwise 1.0), so the
// whole c-path (Wc, bc, tau_m_c, c_out_mem0) is dead code.
//
// Numerics: spike threshold (mem - Bth) > 0 is discontinuous -> recurrence is
// written with `#pragma clang fp contract(off)` in the exact reference op order
// (XLA emits non-contracted fmul/fadd for elementwise HLO; hipcc's default
// -ffp-contract=fast would fuse and drift ~1 ULP/step).
//
// rocprof r3 evidence: top-5 dispatches are all 41-44us harness fillBuffer
// (268MB d_ws re-poison at ~80% HBM peak); snn_fused < 41us. The scored
// dur_us=112 is mostly harness reset/replay overhead.

constexpr int H_DIM = 64;
constexpr int IN_DIM = 8;
constexpr int O_DIM = 4;
constexpr int TSTEPS = 16;

__global__ __launch_bounds__(256, 4) void snn_fused(
    const float* __restrict__ x,           // [B,8]
    const float* __restrict__ W1,          // [64,8]
    const float* __restrict__ b1,          // [64]
    const float* __restrict__ Wa,          // [4,64]
    const float* __restrict__ ba,          // [4]
    const float* __restrict__ tau_adp_h1,  // [64]
    const float* __restrict__ tau_m_h1,    // [64]
    const float* __restrict__ tau_m_a,     // [4]
    const float* __restrict__ hid1_mem0,   // [B,64]
    const float* __restrict__ a_out_mem0,  // [B,4]
    float* __restrict__ out_val,           // [B]
    float* __restrict__ out_act,           // [B,4]
    int B)
{
    const int lane = threadIdx.x & 63;
    const int li   = lane & 15;  // lane within 16-lane row-group
    const int sub  = lane >> 4;  // row within wave (0..3)
    const int gw   = (blockIdx.x * blockDim.x + threadIdx.x) >> 6;
    const int row  = gw * 4 + sub;
    if (row >= B) return;

    const int h0 = li * 4;       // this lane's 4 hidden channels

    float alpha[4], ro[4], omro[4], ch[4];
    float wa0[4], wa1[4], wa2[4], wa3[4];
    float mem[4], bb[4], spk[4];

    {
        float4 t0 = *(const float4*)(tau_m_h1 + h0);
        float4 a0 = *(const float4*)(tau_adp_h1 + h0);
        float tm[4] = {t0.x, t0.y, t0.z, t0.w};
        float td[4] = {a0.x, a0.y, a0.z, a0.w};
#pragma unroll
        for (int k = 0; k < 4; ++k) {
            alpha[k] = expf(-1.0f / tm[k]);   // accurate exp: feeds the threshold path
            ro[k]    = expf(-1.0f / td[k]);
            omro[k]  = 1.0f - ro[k];
        }
    }

    // ---- input projection: inpt = x @ W1.T + b1 ; ch = (1-alpha)*R_M*inpt ----
    {
#pragma clang fp contract(off)
        float4 xa = *(const float4*)(x + (size_t)row * IN_DIM);
        float4 xb = *(const float4*)(x + (size_t)row * IN_DIM + 4);
        float4 bv = *(const float4*)(b1 + h0);
        float b1v[4] = {bv.x, bv.y, bv.z, bv.w};
#pragma unroll
        for (int k = 0; k < 4; ++k) {
            float4 w_0 = *(const float4*)(W1 + (h0 + k) * IN_DIM);
            float4 w_1 = *(const float4*)(W1 + (h0 + k) * IN_DIM + 4);
            // dot over IN=8: fma chain, same order as the r2 (passing) kernel.
            float ip = b1v[k];
            ip = fmaf(xa.x, w_0.x, ip); ip = fmaf(xa.y, w_0.y, ip);
            ip = fmaf(xa.z, w_0.z, ip); ip = fmaf(xa.w, w_0.w, ip);
            ip = fmaf(xb.x, w_1.x, ip); ip = fmaf(xb.y, w_1.y, ip);
            ip = fmaf(xb.z, w_1.z, ip); ip = fmaf(xb.w, w_1.w, ip);
            ch[k] = (1.0f - alpha[k]) * ip;   // (1-a)*R_M*inpt, R_M==1.0 (exact)
        }
    }

    // ---- Wa fragments: lane holds Wa[o][h0..h0+3] for o=0..3 ----
#define LOADW(dst, o)                                              \
    {                                                              \
        float4 p = *(const float4*)(Wa + (o) * H_DIM + h0);        \
        dst[0] = p.x; dst[1] = p.y; dst[2] = p.z; dst[3] = p.w;    \
    }
    LOADW(wa0, 0) LOADW(wa1, 1) LOADW(wa2, 2) LOADW(wa3, 3)
#undef LOADW

    {
        float4 m0 = *(const float4*)(hid1_mem0 + (size_t)row * H_DIM + h0);
        mem[0] = m0.x; mem[1] = m0.y; mem[2] = m0.z; mem[3] = m0.w;
#pragma unroll
        for (int k = 0; k < 4; ++k) { spk[k] = 0.0f; bb[k] = 0.01f; }
    }

    float al_a[4], oma_a[4], bav[4], am[4], acc[4];
    {
        float4 ta = *(const float4*)(tau_m_a);
        al_a[0] = expf(-1.0f / ta.x); al_a[1] = expf(-1.0f / ta.y);
        al_a[2] = expf(-1.0f / ta.z); al_a[3] = expf(-1.0f / ta.w);
#pragma unroll
        for (int o = 0; o < 4; ++o) oma_a[o] = 1.0f - al_a[o];
        float4 bb4 = *(const float4*)(ba);
        bav[0] = bb4.x; bav[1] = bb4.y; bav[2] = bb4.z; bav[3] = bb4.w;
        float4 am4 = *(const float4*)(a_out_mem0 + (size_t)row * O_DIM);
        am[0] = am4.x; am[1] = am4.y; am[2] = am4.z; am[3] = am4.w;
#pragma unroll
        for (int o = 0; o < 4; ++o) acc[o] = 0.0f;
    }

    // ---- T=16 recurrent steps (contract-off, exact reference op order) ----
#pragma unroll 1
    for (int t = 0; t < TSTEPS; ++t) {
#pragma clang fp contract(off)
        float s0 = 0.f, s1 = 0.f, s2 = 0.f, s3 = 0.f;
#pragma unroll
        for (int k = 0; k < 4; ++k) {
            // b = ro*b + (1-ro)*spk_old
            bb[k] = (ro[k] * bb[k]) + (omro[k] * spk[k]);
            // Bth = b_j0 + 1.8*b
            const float Bth = 0.01f + (1.8f * bb[k]);
            // mem = (mem*alpha + (1-alpha)*inpt) - Bth*spk_old
            const float m = ((mem[k] * alpha[k]) + ch[k]) - (Bth * spk[k]);
            mem[k] = m;
            // spike_fn(mem - Bth): nearby subtraction is exact, so
            // (m - Bth) > 0  <=>  m > Bth, bitwise-equivalent.
            const float s = (m > Bth) ? 1.0f : 0.0f;
            spk[k] = s;
            // ia partial dot (dot path: fma, like XLA's reduction)
            s0 = fmaf(s, wa0[k], s0);
            s1 = fmaf(s, wa1[k], s1);
            s2 = fmaf(s, wa2[k], s2);
            s3 = fmaf(s, wa3[k], s3);
        }
        // reduce the 4 partial ia sums across the 16 lanes of this row
#pragma unroll
        for (int msk = 1; msk < 16; msk <<= 1) {
            s0 += __shfl_xor(s0, msk);
            s1 += __shfl_xor(s1, msk);
            s2 += __shfl_xor(s2, msk);
            s3 += __shfl_xor(s3, msk);
        }
        // a_mem = a_mem*alpha_a + (1-alpha_a)*(ia+ba)  (all 16 lanes identical)
        am[0] = (al_a[0] * am[0]) + (oma_a[0] * (s0 + bav[0]));
        am[1] = (al_a[1] * am[1]) + (oma_a[1] * (s1 + bav[1]));
        am[2] = (al_a[2] * am[2]) + (oma_a[2] * (s2 + bav[2]));
        am[3] = (al_a[3] * am[3]) + (oma_a[3] * (s3 + bav[3]));
        const float mx = fmaxf(fmaxf(am[0], am[1]), fmaxf(am[2], am[3]));
        const float e0 = __expf(am[0] - mx);
        const float e1 = __expf(am[1] - mx);
        const float e2 = __expf(am[2] - mx);
        const float e3 = __expf(am[3] - mx);
        const float S = ((e0 + e1) + e2) + e3;
        const float r = 1.0f / S;               // precise divide (continuous path)
        acc[0] = acc[0] + (e0 * r);
        acc[1] = acc[1] + (e1 * r);
        acc[2] = acc[2] + (e2 * r);
        acc[3] = acc[3] + (e3 * r);
    }

    if (li == 0) {
        out_val[row] = 16.0f;  // softmax of a single logit is bitwise 1.0, x16 steps
        *(float4*)(out_act + (size_t)row * O_DIM) =
            make_float4(acc[0], acc[1], acc[2], acc[3]);
    }
}

extern "C" void kernel_launch(void* const* d_in, const int* in_sizes, int n_in,
                              void* d_out, int out_size, void* d_ws, size_t ws_size,
                              hipStream_t stream) {
    // setup_inputs() order:
    //  0:x 1:W1 2:b1 3:Wa 4:ba 5:Wc(dead) 6:bc(dead) 7:tau_adp_h1 8:tau_m_h1
    //  9:tau_m_a 10:tau_m_c(dead) 11:hid1_mem0 12:a_out_mem0 13:c_out_mem0(dead)
    const float* x          = (const float*)d_in[0];
    const float* W1         = (const float*)d_in[1];
    const float* b1         = (const float*)d_in[2];
    const float* Wa         = (const float*)d_in[3];
    const float* ba         = (const float*)d_in[4];
    const float* tau_adp_h1 = (const float*)d_in[7];
    const float* tau_m_h1   = (const float*)d_in[8];
    const float* tau_m_a    = (const float*)d_in[9];
    const float* hid1_mem0  = (const float*)d_in[11];
    const float* a_out_mem0 = (const float*)d_in[12];

    const int B = in_sizes[11] / H_DIM;   // from hid1_mem0 [B,64] -> 32768
    float* out_val = (float*)d_out;       // [B]  (val, flattened [B,1])
    float* out_act = (float*)d_out + B;   // [B,4]

    const int rows_per_block = 16;        // 256 threads = 4 waves x 4 rows each
    const int blocks = (B + rows_per_block - 1) / rows_per_block;
    snn_fused<<<blocks, 256, 0, stream>>>(x, W1, b1, Wa, ba, tau_adp_h1,
                                          tau_m_h1, tau_m_a, hid1_mem0,
                                          a_out_mem0, out_val, out_act, B);
}

// Round 8
// 113.118 us; speedup vs baseline: 1.0191x; 1.0191x over previous
//
#include <hip/hip_runtime.h>

// SNN policy rollout, fully fused. B=32768 rows, H=64 hidden, O=4 outputs, T=16 steps.
//
// Mapping: 256-thread block = 4 waves = 16 rows. Per wave: 4 rows x 16 lanes/row,
// each lane owns 4 h-channels (h = li*4..li*4+3). r5 profile: VGPR=40, VALUBusy=61%,
// 39% stall, kernel 40.5us, HBM 1.7% -> pure VALU/latency-bound.
//
// r6 changes (attack the 39% stall + trim VALU):
//  1. T-loop unroll 4 (was unroll 1): lets the scheduler overlap the k-loop of
//     step t+1 (needs only spk(t)) with the butterfly/softmax tail of step t.
//  2. Butterfly masks 1,2,8 via DPP (quad_perm 0xB1 / 0x4E, row_ror:8 0x128) --
//     full-rate VALU adds (GCNDPPCombine fuses update_dpp+fadd into v_add_f32_dpp),
//     no LDS pipe, no lgkmcnt. Only mask 4 remains a real shuffle: butterfly depth
//     4 DS stages -> 1 DS stage. DPP row = 16 lanes = exactly our row group; all
//     64 lanes are always active (grid exact), so DPP is safe.
//  3. Softmax divide via rcp (continuous path only; ~1e-6, tolerance is 0.03).
// Spike-threshold path is UNTOUCHED: contract(off), exact reference op order --
// bit-identical to the r3/r5 passing runs (absmax 0.03125, rare spike flips).
//
// val output is exactly 16.0 (softmax of a [B,1] tensor is bitwise 1.0): the
// whole c-path (Wc, bc, tau_m_c, c_out_mem0) is dead code.

constexpr int H_DIM = 64;
constexpr int IN_DIM = 8;
constexpr int O_DIM = 4;
constexpr int TSTEPS = 16;

// v + dpp_shuffle(v); CTRL: 0xB1=xor1, 0x4E=xor2, 0x128=xor8 (within 16-lane row)
template <int CTRL>
__device__ __forceinline__ float dpp_add(float v) {
    int s = __builtin_amdgcn_update_dpp(0, __float_as_int(v), CTRL, 0xF, 0xF, true);
    return v + __int_as_float(s);
}

__global__ __launch_bounds__(256, 4) void snn_fused(
    const float* __restrict__ x,           // [B,8]
    const float* __restrict__ W1,          // [64,8]
    const float* __restrict__ b1,          // [64]
    const float* __restrict__ Wa,          // [4,64]
    const float* __restrict__ ba,          // [4]
    const float* __restrict__ tau_adp_h1,  // [64]
    const float* __restrict__ tau_m_h1,    // [64]
    const float* __restrict__ tau_m_a,     // [4]
    const float* __restrict__ hid1_mem0,   // [B,64]
    const float* __restrict__ a_out_mem0,  // [B,4]
    float* __restrict__ out_val,           // [B]
    float* __restrict__ out_act,           // [B,4]
    int B)
{
    const int lane = threadIdx.x & 63;
    const int li   = lane & 15;  // lane within 16-lane row-group
    const int sub  = lane >> 4;  // row within wave (0..3)
    const int gw   = (blockIdx.x * blockDim.x + threadIdx.x) >> 6;
    const int row  = gw * 4 + sub;
    if (row >= B) return;        // never taken: grid exact (B % 16 == 0)

    const int h0 = li * 4;       // this lane's 4 hidden channels

    float alpha[4], ro[4], omro[4], ch[4];
    float wa0[4], wa1[4], wa2[4], wa3[4];
    float mem[4], bb[4], spk[4];

    {
        float4 t0 = *(const float4*)(tau_m_h1 + h0);
        float4 a0 = *(const float4*)(tau_adp_h1 + h0);
        float tm[4] = {t0.x, t0.y, t0.z, t0.w};
        float td[4] = {a0.x, a0.y, a0.z, a0.w};
#pragma unroll
        for (int k = 0; k < 4; ++k) {
            alpha[k] = expf(-1.0f / tm[k]);   // accurate exp: feeds the threshold path
            ro[k]    = expf(-1.0f / td[k]);
            omro[k]  = 1.0f - ro[k];
        }
    }

    // ---- input projection: inpt = x @ W1.T + b1 ; ch = (1-alpha)*R_M*inpt ----
    {
#pragma clang fp contract(off)
        float4 xa = *(const float4*)(x + (size_t)row * IN_DIM);
        float4 xb = *(const float4*)(x + (size_t)row * IN_DIM + 4);
        float4 bv = *(const float4*)(b1 + h0);
        float b1v[4] = {bv.x, bv.y, bv.z, bv.w};
#pragma unroll
        for (int k = 0; k < 4; ++k) {
            float4 w_0 = *(const float4*)(W1 + (h0 + k) * IN_DIM);
            float4 w_1 = *(const float4*)(W1 + (h0 + k) * IN_DIM + 4);
            // dot over IN=8: fma chain, same order as the passing r3/r5 kernels.
            float ip = b1v[k];
            ip = fmaf(xa.x, w_0.x, ip); ip = fmaf(xa.y, w_0.y, ip);
            ip = fmaf(xa.z, w_0.z, ip); ip = fmaf(xa.w, w_0.w, ip);
            ip = fmaf(xb.x, w_1.x, ip); ip = fmaf(xb.y, w_1.y, ip);
            ip = fmaf(xb.z, w_1.z, ip); ip = fmaf(xb.w, w_1.w, ip);
            ch[k] = (1.0f - alpha[k]) * ip;   // (1-a)*R_M*inpt, R_M==1.0 (exact)
        }
    }

    // ---- Wa fragments: lane holds Wa[o][h0..h0+3] for o=0..3 ----
#define LOADW(dst, o)                                              \
    {                                                              \
        float4 p = *(const float4*)(Wa + (o) * H_DIM + h0);        \
        dst[0] = p.x; dst[1] = p.y; dst[2] = p.z; dst[3] = p.w;    \
    }
    LOADW(wa0, 0) LOADW(wa1, 1) LOADW(wa2, 2) LOADW(wa3, 3)
#undef LOADW

    {
        float4 m0 = *(const float4*)(hid1_mem0 + (size_t)row * H_DIM + h0);
        mem[0] = m0.x; mem[1] = m0.y; mem[2] = m0.z; mem[3] = m0.w;
#pragma unroll
        for (int k = 0; k < 4; ++k) { spk[k] = 0.0f; bb[k] = 0.01f; }
    }

    float al_a[4], oma_a[4], bav[4], am[4], acc[4];
    {
        float4 ta = *(const float4*)(tau_m_a);
        al_a[0] = expf(-1.0f / ta.x); al_a[1] = expf(-1.0f / ta.y);
        al_a[2] = expf(-1.0f / ta.z); al_a[3] = expf(-1.0f / ta.w);
#pragma unroll
        for (int o = 0; o < 4; ++o) oma_a[o] = 1.0f - al_a[o];
        float4 bb4 = *(const float4*)(ba);
        bav[0] = bb4.x; bav[1] = bb4.y; bav[2] = bb4.z; bav[3] = bb4.w;
        float4 am4 = *(const float4*)(a_out_mem0 + (size_t)row * O_DIM);
        am[0] = am4.x; am[1] = am4.y; am[2] = am4.z; am[3] = am4.w;
#pragma unroll
        for (int o = 0; o < 4; ++o) acc[o] = 0.0f;
    }

    // ---- T=16 recurrent steps; unroll 4 exposes cross-step ILP (kloop(t+1)
    //      only needs spk(t), so it can overlap butterfly/softmax of step t) ----
#pragma unroll 4
    for (int t = 0; t < TSTEPS; ++t) {
#pragma clang fp contract(off)
        float s0 = 0.f, s1 = 0.f, s2 = 0.f, s3 = 0.f;
#pragma unroll
        for (int k = 0; k < 4; ++k) {
            // b = ro*b + (1-ro)*spk_old
            bb[k] = (ro[k] * bb[k]) + (omro[k] * spk[k]);
            // Bth = b_j0 + 1.8*b
            const float Bth = 0.01f + (1.8f * bb[k]);
            // mem = (mem*alpha + (1-alpha)*inpt) - Bth*spk_old
            const float m = ((mem[k] * alpha[k]) + ch[k]) - (Bth * spk[k]);
            mem[k] = m;
            // spike_fn(mem - Bth): nearby subtraction is exact, so
            // (m - Bth) > 0  <=>  m > Bth, bitwise-equivalent.
            const float s = (m > Bth) ? 1.0f : 0.0f;
            spk[k] = s;
            // ia partial dot (dot path: fma, like XLA's reduction)
            s0 = fmaf(s, wa0[k], s0);
            s1 = fmaf(s, wa1[k], s1);
            s2 = fmaf(s, wa2[k], s2);
            s3 = fmaf(s, wa3[k], s3);
        }
        // reduce across the 16 lanes of this row: xor1/xor2/xor8 are DPP
        // (full-rate VALU, no LDS pipe); only xor4 is a real shuffle.
        s0 = dpp_add<0xB1>(s0);  s1 = dpp_add<0xB1>(s1);
        s2 = dpp_add<0xB1>(s2);  s3 = dpp_add<0xB1>(s3);
        s0 = dpp_add<0x4E>(s0);  s1 = dpp_add<0x4E>(s1);
        s2 = dpp_add<0x4E>(s2);  s3 = dpp_add<0x4E>(s3);
        s0 = dpp_add<0x128>(s0); s1 = dpp_add<0x128>(s1);
        s2 = dpp_add<0x128>(s2); s3 = dpp_add<0x128>(s3);
        s0 += __shfl_xor(s0, 4);
        s1 += __shfl_xor(s1, 4);
        s2 += __shfl_xor(s2, 4);
        s3 += __shfl_xor(s3, 4);
        // a_mem = a_mem*alpha_a + (1-alpha_a)*(ia+ba)  (all 16 lanes identical)
        am[0] = (al_a[0] * am[0]) + (oma_a[0] * (s0 + bav[0]));
        am[1] = (al_a[1] * am[1]) + (oma_a[1] * (s1 + bav[1]));
        am[2] = (al_a[2] * am[2]) + (oma_a[2] * (s2 + bav[2]));
        am[3] = (al_a[3] * am[3]) + (oma_a[3] * (s3 + bav[3]));
        const float mx = fmaxf(fmaxf(am[0], am[1]), fmaxf(am[2], am[3]));
        const float e0 = __expf(am[0] - mx);
        const float e1 = __expf(am[1] - mx);
        const float e2 = __expf(am[2] - mx);
        const float e3 = __expf(am[3] - mx);
        const float S = ((e0 + e1) + e2) + e3;
        const float r = __builtin_amdgcn_rcpf(S);   // continuous path, ~1e-6
        acc[0] = acc[0] + (e0 * r);
        acc[1] = acc[1] + (e1 * r);
        acc[2] = acc[2] + (e2 * r);
        acc[3] = acc[3] + (e3 * r);
    }

    if (li == 0) {
        out_val[row] = 16.0f;  // softmax of a single logit is bitwise 1.0, x16 steps
        *(float4*)(out_act + (size_t)row * O_DIM) =
            make_float4(acc[0], acc[1], acc[2], acc[3]);
    }
}

extern "C" void kernel_launch(void* const* d_in, const int* in_sizes, int n_in,
                              void* d_out, int out_size, void* d_ws, size_t ws_size,
                              hipStream_t stream) {
    // setup_inputs() order:
    //  0:x 1:W1 2:b1 3:Wa 4:ba 5:Wc(dead) 6:bc(dead) 7:tau_adp_h1 8:tau_m_h1
    //  9:tau_m_a 10:tau_m_c(dead) 11:hid1_mem0 12:a_out_mem0 13:c_out_mem0(dead)
    const float* x          = (const float*)d_in[0];
    const float* W1         = (const float*)d_in[1];
    const float* b1         = (const float*)d_in[2];
    const float* Wa         = (const float*)d_in[3];
    const float* ba         = (const float*)d_in[4];
    const float* tau_adp_h1 = (const float*)d_in[7];
    const float* tau_m_h1   = (const float*)d_in[8];
    const float* tau_m_a    = (const float*)d_in[9];
    const float* hid1_mem0  = (const float*)d_in[11];
    const float* a_out_mem0 = (const float*)d_in[12];

    const int B = in_sizes[11] / H_DIM;   // from hid1_mem0 [B,64] -> 32768
    float* out_val = (float*)d_out;       // [B]  (val, flattened [B,1])
    float* out_act = (float*)d_out + B;   // [B,4]

    const int rows_per_block = 16;        // 256 threads = 4 waves x 4 rows each
    const int blocks = (B + rows_per_block - 1) / rows_per_block;
    snn_fused<<<blocks, 256, 0, stream>>>(x, W1, b1, Wa, ba, tau_adp_h1,
                                          tau_m_h1, tau_m_a, hid1_mem0,
                                          a_out_mem0, out_val, out_act, B);
}